// Round 2
// baseline (3371.488 us; speedup 1.0000x reference)
//
#include <hip/hip_runtime.h>
#include <hip/hip_bf16.h>

#define N_NODES 100000
#define N_EDGES 1600000
#define E_TOT   (N_EDGES + N_NODES)   // edges + self loops
#define F 128
#define NGRAPH 64
#define NEG_SLOPE 0.2f
#define SELU_SCALE 1.0507009873554805f
#define SELU_ALPHA 1.6732632423543772f

__device__ __forceinline__ float selu_f(float x) {
    return x > 0.f ? SELU_SCALE * x : SELU_SCALE * SELU_ALPHA * (expf(x) - 1.f);
}
// order-preserving float->uint key for atomicMax
__device__ __forceinline__ unsigned fkey(float f) {
    unsigned u = __float_as_uint(f);
    return (u & 0x80000000u) ? ~u : (u | 0x80000000u);
}
__device__ __forceinline__ float funkey(unsigned k) {
    unsigned u = (k & 0x80000000u) ? (k & 0x7FFFFFFFu) : ~k;
    return __uint_as_float(u);
}
#define KEY_NEG_INF 0x007FFFFFu   // fkey(-inf)

// ---------------- GEMM: H[n,128] = X[n,128] @ W[128,128], f32 ---------------
__global__ __launch_bounds__(256) void gemm128(const float* __restrict__ X,
                                               const float* __restrict__ W,
                                               float* __restrict__ H, int nrows) {
    __shared__ float Xs[32][F];
    int row0 = blockIdx.x * 32;
    for (int i = threadIdx.x; i < 32 * F; i += 256) {
        int r = i >> 7, c = i & 127;
        int gr = row0 + r;
        Xs[r][c] = (gr < nrows) ? X[(size_t)gr * F + c] : 0.f;
    }
    __syncthreads();
    int cg = (threadIdx.x & 31) * 4;   // 4 consecutive cols
    int rg = (threadIdx.x >> 5) * 4;   // 4 consecutive rows
    float acc[4][4] = {};
    for (int k = 0; k < F; ++k) {
        float4 wv = *(const float4*)(W + (size_t)k * F + cg);
#pragma unroll
        for (int j = 0; j < 4; ++j) {
            float xv = Xs[rg + j][k];
            acc[j][0] += xv * wv.x; acc[j][1] += xv * wv.y;
            acc[j][2] += xv * wv.z; acc[j][3] += xv * wv.w;
        }
    }
    for (int j = 0; j < 4; ++j) {
        int gr = row0 + rg + j;
        if (gr < nrows) {
            float4 o = make_float4(acc[j][0], acc[j][1], acc[j][2], acc[j][3]);
            *(float4*)(H + (size_t)gr * F + cg) = o;
        }
    }
}

// ------------- per-node alpha_src/alpha_dst dots + init m/z + zero acc ------
__global__ __launch_bounds__(256) void alphas_init(const float* __restrict__ H,
                                                   const float* __restrict__ avs,
                                                   const float* __restrict__ avd,
                                                   float* __restrict__ as_, float* __restrict__ ad_,
                                                   unsigned* __restrict__ mkey, float* __restrict__ z,
                                                   float* __restrict__ acc, int n) {
    int wid = (blockIdx.x * 256 + threadIdx.x) >> 6;
    int lane = threadIdx.x & 63;
    if (wid >= n) return;
    float2 h2 = *(const float2*)(H + (size_t)wid * F + lane * 2);
    float2 vs = *(const float2*)(avs + lane * 2);
    float2 vd = *(const float2*)(avd + lane * 2);
    float s = h2.x * vs.x + h2.y * vs.y;
    float d = h2.x * vd.x + h2.y * vd.y;
    *(float2*)(acc + (size_t)wid * F + lane * 2) = make_float2(0.f, 0.f);
#pragma unroll
    for (int off = 32; off; off >>= 1) {
        s += __shfl_down(s, off);
        d += __shfl_down(d, off);
    }
    if (lane == 0) {
        as_[wid] = s; ad_[wid] = d;
        mkey[wid] = KEY_NEG_INF; z[wid] = 0.f;
    }
}

__device__ __forceinline__ void edge_sd(const int* __restrict__ ei, int i, int& s, int& d) {
    if (i < N_EDGES) { s = ei[i]; d = ei[N_EDGES + i]; }
    else             { s = d = i - N_EDGES; }
}

// --------- pass1: e = leakyrelu(as[src]+ad[dst]); segment max over dst ------
__global__ __launch_bounds__(256) void edge_pass1(const int* __restrict__ ei,
                                                  const float* __restrict__ as_,
                                                  const float* __restrict__ ad_,
                                                  unsigned* __restrict__ mkey,
                                                  float* __restrict__ ebuf) {
    int i = blockIdx.x * 256 + threadIdx.x;
    if (i >= E_TOT) return;
    int s, d; edge_sd(ei, i, s, d);
    float e = as_[s] + ad_[d];
    e = e > 0.f ? e : NEG_SLOPE * e;
    ebuf[i] = e;
    atomicMax(&mkey[d], fkey(e));
}

// --------- pass2: ex = exp(e - m[dst]); z[dst] += ex ------------------------
__global__ __launch_bounds__(256) void edge_pass2(const int* __restrict__ ei,
                                                  const unsigned* __restrict__ mkey,
                                                  float* __restrict__ z,
                                                  float* __restrict__ ebuf) {
    int i = blockIdx.x * 256 + threadIdx.x;
    if (i >= E_TOT) return;
    int s, d; edge_sd(ei, i, s, d);
    float m = funkey(mkey[d]);
    float ex = expf(ebuf[i] - m);
    ebuf[i] = ex;
    atomicAdd(&z[d], ex);
}

// --------- pass3: acc[dst] += h[src] * (ex / z[dst]) — one wave per edge ----
__global__ __launch_bounds__(256) void edge_agg(const int* __restrict__ ei,
                                                const float* __restrict__ ebuf,
                                                const float* __restrict__ z,
                                                const float* __restrict__ H,
                                                float* __restrict__ acc) {
    int wid = (blockIdx.x * 256 + threadIdx.x) >> 6;
    int lane = threadIdx.x & 63;
    if (wid >= E_TOT) return;
    int s, d; edge_sd(ei, wid, s, d);
    float a = ebuf[wid] / z[d];
    float2 h2 = *(const float2*)(H + (size_t)s * F + lane * 2);
    float* dst = acc + (size_t)d * F + lane * 2;
    atomicAdd(dst, h2.x * a);
    atomicAdd(dst + 1, h2.y * a);
}

// --------- out = selu(acc + b), in place ------------------------------------
__global__ __launch_bounds__(256) void bias_selu(float* __restrict__ acc,
                                                 const float* __restrict__ b, int n) {
    long i = (long)blockIdx.x * 256 + threadIdx.x;
    if (i >= (long)n * F) return;
    float x = acc[i] + b[(int)(i & 127)];
    acc[i] = selu_f(x);
}

// --------- pooling ----------------------------------------------------------
__device__ __forceinline__ int lower_bound(const int* __restrict__ b, int v) {
    int lo = 0, hi = N_NODES;
    while (lo < hi) { int mid = (lo + hi) >> 1; if (b[mid] < v) lo = mid + 1; else hi = mid; }
    return lo;
}

__global__ __launch_bounds__(128) void pool_partial(const float* __restrict__ X,
                                                    const int* __restrict__ batch,
                                                    float* __restrict__ gsum) {
    int g = blockIdx.x >> 3, c = blockIdx.x & 7;
    int start = lower_bound(batch, g);
    int end = lower_bound(batch, g + 1);
    int len = end - start;
    int s0 = start + (int)((long)len * c / 8);
    int s1 = start + (int)((long)len * (c + 1) / 8);
    if (s1 <= s0) return;
    int f = threadIdx.x;
    float sum = 0.f;
    for (int i = s0; i < s1; ++i) sum += X[(size_t)i * F + f];
    atomicAdd(&gsum[g * F + f], sum);
}

__global__ __launch_bounds__(128) void pool_final(const float* __restrict__ gsum,
                                                  const int* __restrict__ batch,
                                                  float* __restrict__ pooled) {
    int g = blockIdx.x, f = threadIdx.x;
    int cnt = lower_bound(batch, g + 1) - lower_bound(batch, g);
    float c = fmaxf((float)cnt, 1.f);
    pooled[g * F + f] = selu_f(gsum[g * F + f] / c);
}

// --------- MLP head: feat = selu(pooled@fc1+b); logits = feat@fc2+b ---------
__global__ __launch_bounds__(64) void head(const float* __restrict__ pooled,
                                           const float* __restrict__ fc1w,
                                           const float* __restrict__ fc1b,
                                           const float* __restrict__ fc2w,
                                           const float* __restrict__ fc2b,
                                           float* __restrict__ out) {
    __shared__ float fs[64];
    int g = blockIdx.x, j = threadIdx.x;
    float acc = fc1b[j];
    for (int k = 0; k < F; ++k) acc += pooled[g * F + k] * fc1w[k * 64 + j];
    float f = selu_f(acc);
    fs[j] = f;
    out[128 + g * 64 + j] = f;   // feat after logits block
    __syncthreads();
    if (j < 2) {
        float l = fc2b[j];
        for (int k = 0; k < 64; ++k) l += fs[k] * fc2w[k * 2 + j];
        out[g * 2 + j] = l;
    }
}

extern "C" void kernel_launch(void* const* d_in, const int* in_sizes, int n_in,
                              void* d_out, int out_size, void* d_ws, size_t ws_size,
                              hipStream_t stream) {
    const float* x    = (const float*)d_in[0];
    const int*   ei   = (const int*)d_in[1];
    const int*   batch= (const int*)d_in[2];
    const float* W1   = (const float*)d_in[3];
    const float* as1  = (const float*)d_in[4];
    const float* ad1  = (const float*)d_in[5];
    const float* b1   = (const float*)d_in[6];
    const float* W2   = (const float*)d_in[7];
    const float* as2  = (const float*)d_in[8];
    const float* ad2  = (const float*)d_in[9];
    const float* b2   = (const float*)d_in[10];
    const float* fc1w = (const float*)d_in[11];
    const float* fc1b = (const float*)d_in[12];
    const float* fc2w = (const float*)d_in[13];
    const float* fc2b = (const float*)d_in[14];
    float* out = (float*)d_out;

    float* A      = (float*)d_ws;                 // N*128
    float* B      = A + (size_t)N_NODES * F;      // N*128
    float* as_    = B + (size_t)N_NODES * F;      // N
    float* ad_    = as_ + N_NODES;                // N
    unsigned* mk  = (unsigned*)(ad_ + N_NODES);   // N
    float* z      = (float*)(mk + N_NODES);       // N
    float* ebuf   = z + N_NODES;                  // E_TOT
    float* gsum   = ebuf + E_TOT;                 // 64*128
    float* pooled = gsum + NGRAPH * F;            // 64*128

    hipMemsetAsync(gsum, 0, NGRAPH * F * sizeof(float), stream);

    const int gGemm  = N_NODES / 32 + 1;          // cover 100000 rows (3126)
    const int gNode  = (N_NODES + 3) / 4;         // wave per node
    const int gEdge  = (E_TOT + 255) / 256;
    const int gEdgeW = (E_TOT + 3) / 4;           // wave per edge
    const int gElem  = (N_NODES * F + 255) / 256;

    // ---- layer 1: x -> A = h1 ; aggregate into B ----
    gemm128<<<gGemm, 256, 0, stream>>>(x, W1, A, N_NODES);
    alphas_init<<<gNode, 256, 0, stream>>>(A, as1, ad1, as_, ad_, mk, z, B, N_NODES);
    edge_pass1<<<gEdge, 256, 0, stream>>>(ei, as_, ad_, mk, ebuf);
    edge_pass2<<<gEdge, 256, 0, stream>>>(ei, mk, z, ebuf);
    edge_agg<<<gEdgeW, 256, 0, stream>>>(ei, ebuf, z, A, B);
    bias_selu<<<gElem, 256, 0, stream>>>(B, b1, N_NODES);

    // ---- layer 2: B -> A = h2 ; aggregate into B ----
    gemm128<<<gGemm, 256, 0, stream>>>(B, W2, A, N_NODES);
    alphas_init<<<gNode, 256, 0, stream>>>(A, as2, ad2, as_, ad_, mk, z, B, N_NODES);
    edge_pass1<<<gEdge, 256, 0, stream>>>(ei, as_, ad_, mk, ebuf);
    edge_pass2<<<gEdge, 256, 0, stream>>>(ei, mk, z, ebuf);
    edge_agg<<<gEdgeW, 256, 0, stream>>>(ei, ebuf, z, A, B);
    bias_selu<<<gElem, 256, 0, stream>>>(B, b2, N_NODES);

    // ---- pool + head ----
    pool_partial<<<NGRAPH * 8, 128, 0, stream>>>(B, batch, gsum);
    pool_final<<<NGRAPH, 128, 0, stream>>>(gsum, batch, pooled);
    head<<<NGRAPH, 64, 0, stream>>>(pooled, fc1w, fc1b, fc2w, fc2b, out);
}

// Round 3
// 850.454 us; speedup vs baseline: 3.9643x; 3.9643x over previous
//
#include <hip/hip_runtime.h>
#include <hip/hip_bf16.h>

#define N_NODES 100000
#define N_EDGES 1600000
#define E_TOT   (N_EDGES + N_NODES)   // edges + self loops
#define F 128
#define NGRAPH 64
#define NEG_SLOPE 0.2f
#define SELU_SCALE 1.0507009873554805f
#define SELU_ALPHA 1.6732632423543772f
#define SCAN_NB 98                     // ceil(100000/1024)

__device__ __forceinline__ float selu_f(float x) {
    return x > 0.f ? SELU_SCALE * x : SELU_SCALE * SELU_ALPHA * (expf(x) - 1.f);
}
__device__ __forceinline__ float lrelu(float x) {
    return x > 0.f ? x : NEG_SLOPE * x;
}

// ---------------- GEMM: H[n,128] = X[n,128] @ W[128,128], f32 ---------------
__global__ __launch_bounds__(256) void gemm128(const float* __restrict__ X,
                                               const float* __restrict__ W,
                                               float* __restrict__ H, int nrows) {
    __shared__ float Xs[32][F];
    int row0 = blockIdx.x * 32;
    for (int i = threadIdx.x; i < 32 * F; i += 256) {
        int r = i >> 7, c = i & 127;
        int gr = row0 + r;
        Xs[r][c] = (gr < nrows) ? X[(size_t)gr * F + c] : 0.f;
    }
    __syncthreads();
    int cg = (threadIdx.x & 31) * 4;
    int rg = (threadIdx.x >> 5) * 4;
    float acc[4][4] = {};
    for (int k = 0; k < F; ++k) {
        float4 wv = *(const float4*)(W + (size_t)k * F + cg);
#pragma unroll
        for (int j = 0; j < 4; ++j) {
            float xv = Xs[rg + j][k];
            acc[j][0] += xv * wv.x; acc[j][1] += xv * wv.y;
            acc[j][2] += xv * wv.z; acc[j][3] += xv * wv.w;
        }
    }
    for (int j = 0; j < 4; ++j) {
        int gr = row0 + rg + j;
        if (gr < nrows) {
            float4 o = make_float4(acc[j][0], acc[j][1], acc[j][2], acc[j][3]);
            *(float4*)(H + (size_t)gr * F + cg) = o;
        }
    }
}

// ---------------- per-node attention dots -----------------------------------
__global__ __launch_bounds__(256) void alphas(const float* __restrict__ H,
                                              const float* __restrict__ avs,
                                              const float* __restrict__ avd,
                                              float* __restrict__ as_, float* __restrict__ ad_,
                                              int n) {
    int wid = (blockIdx.x * 256 + threadIdx.x) >> 6;
    int lane = threadIdx.x & 63;
    if (wid >= n) return;
    float2 h2 = *(const float2*)(H + (size_t)wid * F + lane * 2);
    float2 vs = *(const float2*)(avs + lane * 2);
    float2 vd = *(const float2*)(avd + lane * 2);
    float s = h2.x * vs.x + h2.y * vs.y;
    float d = h2.x * vd.x + h2.y * vd.y;
#pragma unroll
    for (int off = 32; off; off >>= 1) {
        s += __shfl_down(s, off);
        d += __shfl_down(d, off);
    }
    if (lane == 0) { as_[wid] = s; ad_[wid] = d; }
}

// ---------------- CSR build -------------------------------------------------
__device__ __forceinline__ void edge_sd(const int* __restrict__ ei, int i, int& s, int& d) {
    if (i < N_EDGES) { s = ei[i]; d = ei[N_EDGES + i]; }
    else             { s = d = i - N_EDGES; }
}

__global__ __launch_bounds__(256) void hist(const int* __restrict__ ei, int* __restrict__ deg) {
    int i = blockIdx.x * 256 + threadIdx.x;
    if (i >= E_TOT) return;
    int s, d; edge_sd(ei, i, s, d);
    atomicAdd(&deg[d], 1);
}

// block-level exclusive scan: 1024 elems/block (256 thr x 4)
__global__ __launch_bounds__(256) void scan_a(const int* __restrict__ deg,
                                              int* __restrict__ rowptr,
                                              int* __restrict__ bsum) {
    __shared__ int ts[256];
    int base = blockIdx.x * 1024 + threadIdx.x * 4;
    int v[4]; int s = 0;
#pragma unroll
    for (int j = 0; j < 4; ++j) {
        v[j] = (base + j < N_NODES) ? deg[base + j] : 0;
        s += v[j];
    }
    ts[threadIdx.x] = s;
    __syncthreads();
    for (int off = 1; off < 256; off <<= 1) {
        int t = (threadIdx.x >= off) ? ts[threadIdx.x - off] : 0;
        __syncthreads();
        ts[threadIdx.x] += t;
        __syncthreads();
    }
    int ex = ts[threadIdx.x] - s;
#pragma unroll
    for (int j = 0; j < 4; ++j) {
        if (base + j < N_NODES) rowptr[base + j] = ex;
        ex += v[j];
    }
    if (threadIdx.x == 255) bsum[blockIdx.x] = ts[255];
}

__global__ void scan_b(int* __restrict__ bsum) {
    if (threadIdx.x == 0 && blockIdx.x == 0) {
        int run = 0;
        for (int i = 0; i < SCAN_NB; ++i) { int t = bsum[i]; bsum[i] = run; run += t; }
    }
}

__global__ __launch_bounds__(256) void scan_c(int* __restrict__ rowptr,
                                              const int* __restrict__ bsum) {
    int base = blockIdx.x * 1024 + threadIdx.x * 4;
    int add = bsum[blockIdx.x];
#pragma unroll
    for (int j = 0; j < 4; ++j)
        if (base + j < N_NODES) rowptr[base + j] += add;
    if (blockIdx.x == 0 && threadIdx.x == 0) rowptr[N_NODES] = E_TOT;
}

__global__ __launch_bounds__(256) void scatter(const int* __restrict__ ei,
                                               const int* __restrict__ rowptr,
                                               int* __restrict__ fill,
                                               int* __restrict__ csr_src) {
    int i = blockIdx.x * 256 + threadIdx.x;
    if (i >= E_TOT) return;
    int s, d; edge_sd(ei, i, s, d);
    int pos = rowptr[d] + atomicAdd(&fill[d], 1);
    csr_src[pos] = s;
}

// ------- fused per-dst softmax + aggregation + bias + SELU (no atomics) -----
__global__ __launch_bounds__(256) void gat_csr(const int* __restrict__ rowptr,
                                               const int* __restrict__ csr_src,
                                               const float* __restrict__ as_,
                                               const float* __restrict__ ad_,
                                               const float* __restrict__ H,
                                               const float* __restrict__ bias,
                                               float* __restrict__ out) {
    int v = (blockIdx.x * 256 + threadIdx.x) >> 6;
    int lane = threadIdx.x & 63;
    if (v >= N_NODES) return;
    int start = rowptr[v], end = rowptr[v + 1];
    float ad_v = ad_[v];

    // segment max (lane-parallel over edges)
    float m = -__builtin_inff();
    for (int e = start + lane; e < end; e += 64)
        m = fmaxf(m, lrelu(as_[csr_src[e]] + ad_v));
#pragma unroll
    for (int off = 1; off < 64; off <<= 1)
        m = fmaxf(m, __shfl_xor(m, off));

    // segment sum of exp
    float zs = 0.f;
    for (int e = start + lane; e < end; e += 64)
        zs += expf(lrelu(as_[csr_src[e]] + ad_v) - m);
#pragma unroll
    for (int off = 1; off < 64; off <<= 1)
        zs += __shfl_xor(zs, off);
    float zinv = 1.f / zs;

    // aggregation: lanes over features, sequential over edges
    int f = lane * 2;
    float a0 = 0.f, a1 = 0.f;
    for (int e = start; e < end; ++e) {
        int s = csr_src[e];
        float al = expf(lrelu(as_[s] + ad_v) - m) * zinv;
        float2 h2 = *(const float2*)(H + (size_t)s * F + f);
        a0 += h2.x * al;
        a1 += h2.y * al;
    }
    float2 bv = *(const float2*)(bias + f);
    float2 o = make_float2(selu_f(a0 + bv.x), selu_f(a1 + bv.y));
    *(float2*)(out + (size_t)v * F + f) = o;
}

// --------- pooling ----------------------------------------------------------
__device__ __forceinline__ int lower_bound(const int* __restrict__ b, int v) {
    int lo = 0, hi = N_NODES;
    while (lo < hi) { int mid = (lo + hi) >> 1; if (b[mid] < v) lo = mid + 1; else hi = mid; }
    return lo;
}

__global__ __launch_bounds__(128) void pool_partial(const float* __restrict__ X,
                                                    const int* __restrict__ batch,
                                                    float* __restrict__ gsum) {
    int g = blockIdx.x >> 3, c = blockIdx.x & 7;
    int start = lower_bound(batch, g);
    int end = lower_bound(batch, g + 1);
    int len = end - start;
    int s0 = start + (int)((long)len * c / 8);
    int s1 = start + (int)((long)len * (c + 1) / 8);
    if (s1 <= s0) return;
    int f = threadIdx.x;
    float sum = 0.f;
    for (int i = s0; i < s1; ++i) sum += X[(size_t)i * F + f];
    atomicAdd(&gsum[g * F + f], sum);
}

__global__ __launch_bounds__(128) void pool_final(const float* __restrict__ gsum,
                                                  const int* __restrict__ batch,
                                                  float* __restrict__ pooled) {
    int g = blockIdx.x, f = threadIdx.x;
    int cnt = lower_bound(batch, g + 1) - lower_bound(batch, g);
    float c = fmaxf((float)cnt, 1.f);
    pooled[g * F + f] = selu_f(gsum[g * F + f] / c);
}

// --------- MLP head ---------------------------------------------------------
__global__ __launch_bounds__(64) void head(const float* __restrict__ pooled,
                                           const float* __restrict__ fc1w,
                                           const float* __restrict__ fc1b,
                                           const float* __restrict__ fc2w,
                                           const float* __restrict__ fc2b,
                                           float* __restrict__ out) {
    __shared__ float fs[64];
    int g = blockIdx.x, j = threadIdx.x;
    float acc = fc1b[j];
    for (int k = 0; k < F; ++k) acc += pooled[g * F + k] * fc1w[k * 64 + j];
    float f = selu_f(acc);
    fs[j] = f;
    out[128 + g * 64 + j] = f;
    __syncthreads();
    if (j < 2) {
        float l = fc2b[j];
        for (int k = 0; k < 64; ++k) l += fs[k] * fc2w[k * 2 + j];
        out[g * 2 + j] = l;
    }
}

extern "C" void kernel_launch(void* const* d_in, const int* in_sizes, int n_in,
                              void* d_out, int out_size, void* d_ws, size_t ws_size,
                              hipStream_t stream) {
    const float* x    = (const float*)d_in[0];
    const int*   ei   = (const int*)d_in[1];
    const int*   batch= (const int*)d_in[2];
    const float* W1   = (const float*)d_in[3];
    const float* as1  = (const float*)d_in[4];
    const float* ad1  = (const float*)d_in[5];
    const float* b1   = (const float*)d_in[6];
    const float* W2   = (const float*)d_in[7];
    const float* as2  = (const float*)d_in[8];
    const float* ad2  = (const float*)d_in[9];
    const float* b2   = (const float*)d_in[10];
    const float* fc1w = (const float*)d_in[11];
    const float* fc1b = (const float*)d_in[12];
    const float* fc2w = (const float*)d_in[13];
    const float* fc2b = (const float*)d_in[14];
    float* out = (float*)d_out;

    float* A       = (float*)d_ws;                    // N*128
    float* B       = A + (size_t)N_NODES * F;         // N*128
    float* as_     = B + (size_t)N_NODES * F;         // N
    float* ad_     = as_ + N_NODES;                   // N
    int*   deg     = (int*)(ad_ + N_NODES);           // N (also "fill")
    int*   rowptr  = deg + N_NODES;                   // N+1
    int*   csr_src = rowptr + N_NODES + 1;            // E_TOT
    int*   bsum    = csr_src + E_TOT;                 // SCAN_NB (pad 128)
    float* gsum    = (float*)(bsum + 128);            // 64*128
    float* pooled  = gsum + NGRAPH * F;               // 64*128

    hipMemsetAsync(deg, 0, N_NODES * sizeof(int), stream);
    hipMemsetAsync(gsum, 0, NGRAPH * F * sizeof(float), stream);

    const int gGemm = N_NODES / 32 + 1;
    const int gNode = (N_NODES + 3) / 4;    // wave per node
    const int gEdge = (E_TOT + 255) / 256;

    // ---- CSR build (shared by both layers) ----
    hist<<<gEdge, 256, 0, stream>>>(ei, deg);
    scan_a<<<SCAN_NB, 256, 0, stream>>>(deg, rowptr, bsum);
    scan_b<<<1, 64, 0, stream>>>(bsum);
    scan_c<<<SCAN_NB, 256, 0, stream>>>(rowptr, bsum);
    hipMemsetAsync(deg, 0, N_NODES * sizeof(int), stream);   // reuse as fill
    scatter<<<gEdge, 256, 0, stream>>>(ei, rowptr, deg, csr_src);

    // ---- layer 1: x -> A = h1 ; aggregate -> B ----
    gemm128<<<gGemm, 256, 0, stream>>>(x, W1, A, N_NODES);
    alphas<<<gNode, 256, 0, stream>>>(A, as1, ad1, as_, ad_, N_NODES);
    gat_csr<<<gNode, 256, 0, stream>>>(rowptr, csr_src, as_, ad_, A, b1, B);

    // ---- layer 2: B -> A = h2 ; aggregate -> B ----
    gemm128<<<gGemm, 256, 0, stream>>>(B, W2, A, N_NODES);
    alphas<<<gNode, 256, 0, stream>>>(A, as2, ad2, as_, ad_, N_NODES);
    gat_csr<<<gNode, 256, 0, stream>>>(rowptr, csr_src, as_, ad_, A, b2, B);

    // ---- pool + head ----
    pool_partial<<<NGRAPH * 8, 128, 0, stream>>>(B, batch, gsum);
    pool_final<<<NGRAPH, 128, 0, stream>>>(gsum, batch, pooled);
    head<<<NGRAPH, 64, 0, stream>>>(pooled, fc1w, fc1b, fc2w, fc2b, out);
}

// Round 4
// 631.238 us; speedup vs baseline: 5.3411x; 1.3473x over previous
//
#include <hip/hip_runtime.h>
#include <hip/hip_bf16.h>

#define N_NODES 100000
#define N_EDGES 1600000
#define E_TOT   (N_EDGES + N_NODES)   // edges + self loops
#define F 128
#define NGRAPH 64
#define NEG_SLOPE 0.2f
#define SELU_SCALE 1.0507009873554805f
#define SELU_ALPHA 1.6732632423543772f
#define SCAN_NB 98                     // ceil(100000/1024)

__device__ __forceinline__ float selu_f(float x) {
    return x > 0.f ? SELU_SCALE * x : SELU_SCALE * SELU_ALPHA * (expf(x) - 1.f);
}
__device__ __forceinline__ float lrelu(float x) {
    return x > 0.f ? x : NEG_SLOPE * x;
}
__device__ __forceinline__ unsigned short f2bf(float f) {   // RNE
    unsigned u = __float_as_uint(f);
    return (unsigned short)((u + 0x7FFFu + ((u >> 16) & 1u)) >> 16);
}

// ------ GEMM H=X@W (f32 acc) fused with: bf16 H store + attention dots ------
__global__ __launch_bounds__(256) void gemm128_fused(const float* __restrict__ X,
                                                     const float* __restrict__ W,
                                                     const float* __restrict__ avs,
                                                     const float* __restrict__ avd,
                                                     unsigned short* __restrict__ Hb,
                                                     float* __restrict__ as_,
                                                     float* __restrict__ ad_) {
    __shared__ float Xs[32][F];
    int row0 = blockIdx.x * 32;                 // 3125 blocks cover 100000 exactly
    for (int i = threadIdx.x; i < 32 * F; i += 256) {
        int r = i >> 7, c = i & 127;
        Xs[r][c] = X[(size_t)(row0 + r) * F + c];
    }
    __syncthreads();
    int cg = (threadIdx.x & 31) * 4;
    int rg = (threadIdx.x >> 5) * 4;
    float acc[4][4] = {};
    for (int k = 0; k < F; ++k) {
        float4 wv = *(const float4*)(W + (size_t)k * F + cg);
#pragma unroll
        for (int j = 0; j < 4; ++j) {
            float xv = Xs[rg + j][k];
            acc[j][0] += xv * wv.x; acc[j][1] += xv * wv.y;
            acc[j][2] += xv * wv.z; acc[j][3] += xv * wv.w;
        }
    }
    float4 vs = *(const float4*)(avs + cg);
    float4 vd = *(const float4*)(avd + cg);
#pragma unroll
    for (int j = 0; j < 4; ++j) {
        int gr = row0 + rg + j;
        ushort4 hb;
        hb.x = f2bf(acc[j][0]); hb.y = f2bf(acc[j][1]);
        hb.z = f2bf(acc[j][2]); hb.w = f2bf(acc[j][3]);
        *(ushort4*)(Hb + (size_t)gr * F + cg) = hb;
        float ps = acc[j][0] * vs.x + acc[j][1] * vs.y + acc[j][2] * vs.z + acc[j][3] * vs.w;
        float pd = acc[j][0] * vd.x + acc[j][1] * vd.y + acc[j][2] * vd.z + acc[j][3] * vd.w;
#pragma unroll
        for (int off = 16; off; off >>= 1) {
            ps += __shfl_xor(ps, off);
            pd += __shfl_xor(pd, off);
        }
        if ((threadIdx.x & 31) == 0) { as_[gr] = ps; ad_[gr] = pd; }
    }
}

// ---------------- CSR build -------------------------------------------------
__device__ __forceinline__ void edge_sd(const int* __restrict__ ei, int i, int& s, int& d) {
    if (i < N_EDGES) { s = ei[i]; d = ei[N_EDGES + i]; }
    else             { s = d = i - N_EDGES; }
}

__global__ __launch_bounds__(256) void hist(const int* __restrict__ ei, int* __restrict__ deg) {
    int i = blockIdx.x * 256 + threadIdx.x;
    if (i >= E_TOT) return;
    int s, d; edge_sd(ei, i, s, d);
    atomicAdd(&deg[d], 1);
}

__global__ __launch_bounds__(256) void scan_a(const int* __restrict__ deg,
                                              int* __restrict__ rowptr,
                                              int* __restrict__ bsum) {
    __shared__ int ts[256];
    int base = blockIdx.x * 1024 + threadIdx.x * 4;
    int v[4]; int s = 0;
#pragma unroll
    for (int j = 0; j < 4; ++j) {
        v[j] = (base + j < N_NODES) ? deg[base + j] : 0;
        s += v[j];
    }
    ts[threadIdx.x] = s;
    __syncthreads();
    for (int off = 1; off < 256; off <<= 1) {
        int t = (threadIdx.x >= off) ? ts[threadIdx.x - off] : 0;
        __syncthreads();
        ts[threadIdx.x] += t;
        __syncthreads();
    }
    int ex = ts[threadIdx.x] - s;
#pragma unroll
    for (int j = 0; j < 4; ++j) {
        if (base + j < N_NODES) rowptr[base + j] = ex;
        ex += v[j];
    }
    if (threadIdx.x == 255) bsum[blockIdx.x] = ts[255];
}

__global__ __launch_bounds__(128) void scan_b(int* __restrict__ bsum) {
    __shared__ int ts[128];
    int t = threadIdx.x;
    int v = (t < SCAN_NB) ? bsum[t] : 0;
    ts[t] = v;
    __syncthreads();
    for (int off = 1; off < 128; off <<= 1) {
        int u = (t >= off) ? ts[t - off] : 0;
        __syncthreads();
        ts[t] += u;
        __syncthreads();
    }
    if (t < SCAN_NB) bsum[t] = ts[t] - v;   // exclusive
}

__global__ __launch_bounds__(256) void scan_c(int* __restrict__ rowptr,
                                              const int* __restrict__ bsum) {
    int base = blockIdx.x * 1024 + threadIdx.x * 4;
    int add = bsum[blockIdx.x];
#pragma unroll
    for (int j = 0; j < 4; ++j)
        if (base + j < N_NODES) rowptr[base + j] += add;
    if (blockIdx.x == 0 && threadIdx.x == 0) rowptr[N_NODES] = E_TOT;
}

__global__ __launch_bounds__(256) void scatter(const int* __restrict__ ei,
                                               const int* __restrict__ rowptr,
                                               int* __restrict__ fill,
                                               int* __restrict__ csr_src) {
    int i = blockIdx.x * 256 + threadIdx.x;
    if (i >= E_TOT) return;
    int s, d; edge_sd(ei, i, s, d);
    int pos = rowptr[d] + atomicAdd(&fill[d], 1);
    csr_src[pos] = s;
}

// ------- fused per-dst softmax + aggregation + bias + SELU ------------------
// one wave per node; fast path (deg<=64): 1 gather + 1 expf per edge, shfl broadcast
__global__ __launch_bounds__(256) void gat_csr(const int* __restrict__ rowptr,
                                               const int* __restrict__ csr_src,
                                               const float* __restrict__ as_,
                                               const float* __restrict__ ad_,
                                               const unsigned short* __restrict__ Hb,
                                               const float* __restrict__ bias,
                                               float* __restrict__ out) {
    int v = (blockIdx.x * 256 + threadIdx.x) >> 6;
    int lane = threadIdx.x & 63;
    if (v >= N_NODES) return;
    int start = rowptr[v];
    int deg = rowptr[v + 1] - start;
    float ad_v = ad_[v];
    float a0 = 0.f, a1 = 0.f;
    const unsigned* Hu = (const unsigned*)Hb;   // 2 bf16 per dword

    if (deg <= 64) {
        int  s_reg = (lane < deg) ? csr_src[start + lane] : 0;
        float ev   = (lane < deg) ? lrelu(as_[s_reg] + ad_v) : -__builtin_inff();
        float m = ev;
#pragma unroll
        for (int off = 1; off < 64; off <<= 1) m = fmaxf(m, __shfl_xor(m, off));
        float ex = (lane < deg) ? expf(ev - m) : 0.f;
        float zs = ex;
#pragma unroll
        for (int off = 1; off < 64; off <<= 1) zs += __shfl_xor(zs, off);
        float al_l = ex / zs;                    // per-lane alpha
        for (int e = 0; e < deg; ++e) {
            float al = __shfl(al_l, e);
            int   s  = __shfl(s_reg, e);
            unsigned u = Hu[(s << 6) + lane];
            a0 += __uint_as_float(u << 16) * al;
            a1 += __uint_as_float(u & 0xFFFF0000u) * al;
        }
    } else {
        float m = -__builtin_inff();
        for (int e = start + lane; e < start + deg; e += 64)
            m = fmaxf(m, lrelu(as_[csr_src[e]] + ad_v));
#pragma unroll
        for (int off = 1; off < 64; off <<= 1) m = fmaxf(m, __shfl_xor(m, off));
        float zs = 0.f;
        for (int e = start + lane; e < start + deg; e += 64)
            zs += expf(lrelu(as_[csr_src[e]] + ad_v) - m);
#pragma unroll
        for (int off = 1; off < 64; off <<= 1) zs += __shfl_xor(zs, off);
        float zinv = 1.f / zs;
        for (int e = start; e < start + deg; ++e) {
            int s = csr_src[e];
            float al = expf(lrelu(as_[s] + ad_v) - m) * zinv;
            unsigned u = Hu[(s << 6) + lane];
            a0 += __uint_as_float(u << 16) * al;
            a1 += __uint_as_float(u & 0xFFFF0000u) * al;
        }
    }
    int f = lane * 2;
    float2 bv = *(const float2*)(bias + f);
    float2 o = make_float2(selu_f(a0 + bv.x), selu_f(a1 + bv.y));
    *(float2*)(out + (size_t)v * F + f) = o;
}

// --------- pooling ----------------------------------------------------------
__device__ __forceinline__ int lower_bound(const int* __restrict__ b, int v) {
    int lo = 0, hi = N_NODES;
    while (lo < hi) { int mid = (lo + hi) >> 1; if (b[mid] < v) lo = mid + 1; else hi = mid; }
    return lo;
}

__global__ __launch_bounds__(128) void pool_partial(const float* __restrict__ X,
                                                    const int* __restrict__ batch,
                                                    float* __restrict__ gsum) {
    int g = blockIdx.x >> 3, c = blockIdx.x & 7;
    int start = lower_bound(batch, g);
    int end = lower_bound(batch, g + 1);
    int len = end - start;
    int s0 = start + (int)((long)len * c / 8);
    int s1 = start + (int)((long)len * (c + 1) / 8);
    if (s1 <= s0) return;
    int f = threadIdx.x;
    float sum = 0.f;
    for (int i = s0; i < s1; ++i) sum += X[(size_t)i * F + f];
    atomicAdd(&gsum[g * F + f], sum);
}

__global__ __launch_bounds__(128) void pool_final(const float* __restrict__ gsum,
                                                  const int* __restrict__ batch,
                                                  float* __restrict__ pooled) {
    int g = blockIdx.x, f = threadIdx.x;
    int cnt = lower_bound(batch, g + 1) - lower_bound(batch, g);
    float c = fmaxf((float)cnt, 1.f);
    pooled[g * F + f] = selu_f(gsum[g * F + f] / c);
}

// --------- MLP head ---------------------------------------------------------
__global__ __launch_bounds__(64) void head(const float* __restrict__ pooled,
                                           const float* __restrict__ fc1w,
                                           const float* __restrict__ fc1b,
                                           const float* __restrict__ fc2w,
                                           const float* __restrict__ fc2b,
                                           float* __restrict__ out) {
    __shared__ float fs[64];
    int g = blockIdx.x, j = threadIdx.x;
    float acc = fc1b[j];
    for (int k = 0; k < F; ++k) acc += pooled[g * F + k] * fc1w[k * 64 + j];
    float f = selu_f(acc);
    fs[j] = f;
    out[128 + g * 64 + j] = f;
    __syncthreads();
    if (j < 2) {
        float l = fc2b[j];
        for (int k = 0; k < 64; ++k) l += fs[k] * fc2w[k * 2 + j];
        out[g * 2 + j] = l;
    }
}

extern "C" void kernel_launch(void* const* d_in, const int* in_sizes, int n_in,
                              void* d_out, int out_size, void* d_ws, size_t ws_size,
                              hipStream_t stream) {
    const float* x    = (const float*)d_in[0];
    const int*   ei   = (const int*)d_in[1];
    const int*   batch= (const int*)d_in[2];
    const float* W1   = (const float*)d_in[3];
    const float* as1  = (const float*)d_in[4];
    const float* ad1  = (const float*)d_in[5];
    const float* b1   = (const float*)d_in[6];
    const float* W2   = (const float*)d_in[7];
    const float* as2  = (const float*)d_in[8];
    const float* ad2  = (const float*)d_in[9];
    const float* b2   = (const float*)d_in[10];
    const float* fc1w = (const float*)d_in[11];
    const float* fc1b = (const float*)d_in[12];
    const float* fc2w = (const float*)d_in[13];
    const float* fc2b = (const float*)d_in[14];
    float* out = (float*)d_out;

    float*          B       = (float*)d_ws;                    // N*128 f32
    unsigned short* Hb      = (unsigned short*)(B + (size_t)N_NODES * F);  // N*128 bf16
    float*          as_     = (float*)(Hb + (size_t)N_NODES * F);          // N
    float*          ad_     = as_ + N_NODES;                   // N
    int*            deg     = (int*)(ad_ + N_NODES);           // N (also "fill")
    int*            rowptr  = deg + N_NODES;                   // N+1
    int*            csr_src = rowptr + N_NODES + 1;            // E_TOT
    int*            bsum    = csr_src + E_TOT;                 // SCAN_NB (pad 128)
    float*          gsum    = (float*)(bsum + 128);            // 64*128
    float*          pooled  = gsum + NGRAPH * F;               // 64*128

    hipMemsetAsync(deg, 0, N_NODES * sizeof(int), stream);
    hipMemsetAsync(gsum, 0, NGRAPH * F * sizeof(float), stream);

    const int gGemm = N_NODES / 32;         // 3125, exact
    const int gNode = (N_NODES + 3) / 4;    // wave per node
    const int gEdge = (E_TOT + 255) / 256;

    // ---- CSR build (shared by both layers) ----
    hist<<<gEdge, 256, 0, stream>>>(ei, deg);
    scan_a<<<SCAN_NB, 256, 0, stream>>>(deg, rowptr, bsum);
    scan_b<<<1, 128, 0, stream>>>(bsum);
    scan_c<<<SCAN_NB, 256, 0, stream>>>(rowptr, bsum);
    hipMemsetAsync(deg, 0, N_NODES * sizeof(int), stream);   // reuse as fill
    scatter<<<gEdge, 256, 0, stream>>>(ei, rowptr, deg, csr_src);

    // ---- layer 1: x -> Hb(bf16), as_/ad_ ; aggregate -> B ----
    gemm128_fused<<<gGemm, 256, 0, stream>>>(x, W1, as1, ad1, Hb, as_, ad_);
    gat_csr<<<gNode, 256, 0, stream>>>(rowptr, csr_src, as_, ad_, Hb, b1, B);

    // ---- layer 2: B -> Hb(bf16), as_/ad_ ; aggregate -> B ----
    gemm128_fused<<<gGemm, 256, 0, stream>>>(B, W2, as2, ad2, Hb, as_, ad_);
    gat_csr<<<gNode, 256, 0, stream>>>(rowptr, csr_src, as_, ad_, Hb, b2, B);

    // ---- pool + head ----
    pool_partial<<<NGRAPH * 8, 128, 0, stream>>>(B, batch, gsum);
    pool_final<<<NGRAPH, 128, 0, stream>>>(gsum, batch, pooled);
    head<<<NGRAPH, 64, 0, stream>>>(pooled, fc1w, fc1b, fc2w, fc2b, out);
}

// Round 5
// 489.727 us; speedup vs baseline: 6.8844x; 1.2890x over previous
//
#include <hip/hip_runtime.h>
#include <hip/hip_bf16.h>

#define N_NODES 100000
#define N_EDGES 1600000
#define E_TOT   (N_EDGES + N_NODES)   // edges + self loops
#define F 128
#define NGRAPH 64
#define NEG_SLOPE 0.2f
#define SELU_SCALE 1.0507009873554805f
#define SELU_ALPHA 1.6732632423543772f
#define SCAN_NB 98                     // ceil(100000/1024)

typedef __attribute__((ext_vector_type(8))) short bf16x8;
typedef __attribute__((ext_vector_type(4))) float f32x4;

__device__ __forceinline__ float selu_f(float x) {
    return x > 0.f ? SELU_SCALE * x : SELU_SCALE * SELU_ALPHA * (expf(x) - 1.f);
}
__device__ __forceinline__ float lrelu(float x) {
    return x > 0.f ? x : NEG_SLOPE * x;
}
__device__ __forceinline__ unsigned short f2bf(float f) {   // RNE
    unsigned u = __float_as_uint(f);
    return (unsigned short)((u + 0x7FFFu + ((u >> 16) & 1u)) >> 16);
}
__device__ __forceinline__ float bf_lo(unsigned u) { return __uint_as_float(u << 16); }
__device__ __forceinline__ float bf_hi(unsigned u) { return __uint_as_float(u & 0xFFFF0000u); }

// ---------------- f32 -> bf16 convert (x input) -----------------------------
__global__ __launch_bounds__(256) void cvt_bf16(const float* __restrict__ X,
                                                unsigned short* __restrict__ Xb) {
    int i = blockIdx.x * 256 + threadIdx.x;            // 1.6M threads, 8 elems each
    if (i >= N_NODES * F / 8) return;
    const float4* Xp = (const float4*)X;
    float4 v0 = Xp[i * 2], v1 = Xp[i * 2 + 1];
    uint4 o;
    o.x = ((unsigned)f2bf(v0.y) << 16) | f2bf(v0.x);
    o.y = ((unsigned)f2bf(v0.w) << 16) | f2bf(v0.z);
    o.z = ((unsigned)f2bf(v1.y) << 16) | f2bf(v1.x);
    o.w = ((unsigned)f2bf(v1.w) << 16) | f2bf(v1.z);
    ((uint4*)Xb)[i] = o;
}

// --------- pack W[128][128] f32 into MFMA B-fragment order, bf16 ------------
// Wf[((nt*4 + t)*64 + lane)*8 + j] = W[t*32 + (lane>>4)*8 + j][nt*16 + (lane&15)]
__global__ __launch_bounds__(256) void pack_w(const float* __restrict__ W,
                                              unsigned short* __restrict__ Wf) {
    int i = blockIdx.x * 256 + threadIdx.x;            // 2048
    if (i >= 2048) return;
    int l = i & 63, t = (i >> 6) & 3, nt = i >> 8;
    int kb = t * 32 + (l >> 4) * 8;
    int n  = nt * 16 + (l & 15);
    unsigned short o[8];
#pragma unroll
    for (int j = 0; j < 8; ++j) o[j] = f2bf(W[(size_t)(kb + j) * F + n]);
    uint4 p;
    p.x = ((unsigned)o[1] << 16) | o[0];
    p.y = ((unsigned)o[3] << 16) | o[2];
    p.z = ((unsigned)o[5] << 16) | o[4];
    p.w = ((unsigned)o[7] << 16) | o[6];
    ((uint4*)Wf)[i] = p;
}

// ------ MFMA GEMM: Hb = bf16(Xb @ W) + attention dots, no LDS ---------------
// block = 4 waves, BM=64 rows, BN=128. Wave w owns rows [row0+16w, +16).
__global__ __launch_bounds__(256) void gemm_mfma(const unsigned short* __restrict__ Xb,
                                                 const unsigned short* __restrict__ Wf,
                                                 const float* __restrict__ avs,
                                                 const float* __restrict__ avd,
                                                 unsigned short* __restrict__ Hb,
                                                 float* __restrict__ as_,
                                                 float* __restrict__ ad_) {
    int w = threadIdx.x >> 6, l = threadIdx.x & 63;
    int row0 = blockIdx.x * 64 + w * 16;
    int arow = row0 + (l & 15);
    int arow_c = arow < N_NODES ? arow : N_NODES - 1;   // clamp loads
    f32x4 acc[8] = {};
#pragma unroll
    for (int t = 0; t < 4; ++t) {
        bf16x8 a = *(const bf16x8*)(Xb + (size_t)arow_c * F + t * 32 + (l >> 4) * 8);
#pragma unroll
        for (int nt = 0; nt < 8; ++nt) {
            bf16x8 b = *(const bf16x8*)(Wf + (size_t)((nt * 4 + t) * 64 + l) * 8);
            acc[nt] = __builtin_amdgcn_mfma_f32_16x16x32_bf16(a, b, acc[nt], 0, 0, 0);
        }
    }
    // epilogue: C row = (l>>4)*4 + reg, col = nt*16 + (l&15)
    int c = l & 15;
    float ps[4] = {}, pd[4] = {};
#pragma unroll
    for (int nt = 0; nt < 8; ++nt) {
        float ws = avs[nt * 16 + c];
        float wd = avd[nt * 16 + c];
#pragma unroll
        for (int r = 0; r < 4; ++r) {
            int grow = row0 + (l >> 4) * 4 + r;
            if (grow < N_NODES)
                Hb[(size_t)grow * F + nt * 16 + c] = f2bf(acc[nt][r]);
            ps[r] += acc[nt][r] * ws;
            pd[r] += acc[nt][r] * wd;
        }
    }
#pragma unroll
    for (int r = 0; r < 4; ++r) {
#pragma unroll
        for (int off = 1; off < 16; off <<= 1) {
            ps[r] += __shfl_xor(ps[r], off);
            pd[r] += __shfl_xor(pd[r], off);
        }
    }
    if (c == 0) {
#pragma unroll
        for (int r = 0; r < 4; ++r) {
            int grow = row0 + (l >> 4) * 4 + r;
            if (grow < N_NODES) { as_[grow] = ps[r]; ad_[grow] = pd[r]; }
        }
    }
}

// ---------------- CSR build -------------------------------------------------
__device__ __forceinline__ void edge_sd(const int* __restrict__ ei, int i, int& s, int& d) {
    if (i < N_EDGES) { s = ei[i]; d = ei[N_EDGES + i]; }
    else             { s = d = i - N_EDGES; }
}

__global__ __launch_bounds__(256) void hist(const int* __restrict__ ei, int* __restrict__ deg) {
    int i = blockIdx.x * 256 + threadIdx.x;
    if (i >= E_TOT) return;
    int s, d; edge_sd(ei, i, s, d);
    atomicAdd(&deg[d], 1);
}

__global__ __launch_bounds__(256) void scan_a(const int* __restrict__ deg,
                                              int* __restrict__ rowptr,
                                              int* __restrict__ bsum) {
    __shared__ int ts[256];
    int base = blockIdx.x * 1024 + threadIdx.x * 4;
    int v[4]; int s = 0;
#pragma unroll
    for (int j = 0; j < 4; ++j) {
        v[j] = (base + j < N_NODES) ? deg[base + j] : 0;
        s += v[j];
    }
    ts[threadIdx.x] = s;
    __syncthreads();
    for (int off = 1; off < 256; off <<= 1) {
        int t = (threadIdx.x >= off) ? ts[threadIdx.x - off] : 0;
        __syncthreads();
        ts[threadIdx.x] += t;
        __syncthreads();
    }
    int ex = ts[threadIdx.x] - s;
#pragma unroll
    for (int j = 0; j < 4; ++j) {
        if (base + j < N_NODES) rowptr[base + j] = ex;
        ex += v[j];
    }
    if (threadIdx.x == 255) bsum[blockIdx.x] = ts[255];
}

__global__ __launch_bounds__(128) void scan_b(int* __restrict__ bsum) {
    __shared__ int ts[128];
    int t = threadIdx.x;
    int v = (t < SCAN_NB) ? bsum[t] : 0;
    ts[t] = v;
    __syncthreads();
    for (int off = 1; off < 128; off <<= 1) {
        int u = (t >= off) ? ts[t - off] : 0;
        __syncthreads();
        ts[t] += u;
        __syncthreads();
    }
    if (t < SCAN_NB) bsum[t] = ts[t] - v;   // exclusive
}

__global__ __launch_bounds__(256) void scan_c(int* __restrict__ rowptr,
                                              const int* __restrict__ bsum) {
    int base = blockIdx.x * 1024 + threadIdx.x * 4;
    int add = bsum[blockIdx.x];
#pragma unroll
    for (int j = 0; j < 4; ++j)
        if (base + j < N_NODES) rowptr[base + j] += add;
    if (blockIdx.x == 0 && threadIdx.x == 0) rowptr[N_NODES] = E_TOT;
}

__global__ __launch_bounds__(256) void scatter(const int* __restrict__ ei,
                                               const int* __restrict__ rowptr,
                                               int* __restrict__ fill,
                                               int* __restrict__ csr_src) {
    int i = blockIdx.x * 256 + threadIdx.x;
    if (i >= E_TOT) return;
    int s, d; edge_sd(ei, i, s, d);
    int pos = rowptr[d] + atomicAdd(&fill[d], 1);
    csr_src[pos] = s;
}

// ------- fused per-dst softmax + aggregation + bias + SELU ------------------
// one wave per node; fast path (deg<=64): 1 gather + 1 expf per edge.
// OUT_BF16: write bf16 (feeds next gemm / pool); else f32 (unused now but kept)
template <bool OUT_BF16>
__global__ __launch_bounds__(256) void gat_csr(const int* __restrict__ rowptr,
                                               const int* __restrict__ csr_src,
                                               const float* __restrict__ as_,
                                               const float* __restrict__ ad_,
                                               const unsigned short* __restrict__ Hb,
                                               const float* __restrict__ bias,
                                               void* __restrict__ outp) {
    int v = (blockIdx.x * 256 + threadIdx.x) >> 6;
    int lane = threadIdx.x & 63;
    if (v >= N_NODES) return;
    int start = rowptr[v];
    int deg = rowptr[v + 1] - start;
    float ad_v = ad_[v];
    float a0 = 0.f, a1 = 0.f, b0 = 0.f, b1 = 0.f;
    const unsigned* Hu = (const unsigned*)Hb;   // 2 bf16 per dword

    if (deg <= 64) {
        int  s_reg = (lane < deg) ? csr_src[start + lane] : 0;
        float ev   = (lane < deg) ? lrelu(as_[s_reg] + ad_v) : -__builtin_inff();
        float m = ev;
#pragma unroll
        for (int off = 1; off < 64; off <<= 1) m = fmaxf(m, __shfl_xor(m, off));
        float ex = (lane < deg) ? expf(ev - m) : 0.f;
        float zs = ex;
#pragma unroll
        for (int off = 1; off < 64; off <<= 1) zs += __shfl_xor(zs, off);
        float al_l = ex / zs;                    // per-lane alpha
        int e = 0;
        for (; e + 4 <= deg; e += 4) {           // 4 gathers in flight
            float l0 = __shfl(al_l, e),     l1 = __shfl(al_l, e + 1);
            float l2 = __shfl(al_l, e + 2), l3 = __shfl(al_l, e + 3);
            int   s0 = __shfl(s_reg, e),     s1 = __shfl(s_reg, e + 1);
            int   s2 = __shfl(s_reg, e + 2), s3 = __shfl(s_reg, e + 3);
            unsigned u0 = Hu[(s0 << 6) + lane], u1 = Hu[(s1 << 6) + lane];
            unsigned u2 = Hu[(s2 << 6) + lane], u3 = Hu[(s3 << 6) + lane];
            a0 += bf_lo(u0) * l0; a1 += bf_hi(u0) * l0;
            b0 += bf_lo(u1) * l1; b1 += bf_hi(u1) * l1;
            a0 += bf_lo(u2) * l2; a1 += bf_hi(u2) * l2;
            b0 += bf_lo(u3) * l3; b1 += bf_hi(u3) * l3;
        }
        for (; e < deg; ++e) {
            float al = __shfl(al_l, e);
            int   s  = __shfl(s_reg, e);
            unsigned u = Hu[(s << 6) + lane];
            a0 += bf_lo(u) * al; a1 += bf_hi(u) * al;
        }
    } else {
        float m = -__builtin_inff();
        for (int e = start + lane; e < start + deg; e += 64)
            m = fmaxf(m, lrelu(as_[csr_src[e]] + ad_v));
#pragma unroll
        for (int off = 1; off < 64; off <<= 1) m = fmaxf(m, __shfl_xor(m, off));
        float zs = 0.f;
        for (int e = start + lane; e < start + deg; e += 64)
            zs += expf(lrelu(as_[csr_src[e]] + ad_v) - m);
#pragma unroll
        for (int off = 1; off < 64; off <<= 1) zs += __shfl_xor(zs, off);
        float zinv = 1.f / zs;
        for (int e = start; e < start + deg; ++e) {
            int s = csr_src[e];
            float al = expf(lrelu(as_[s] + ad_v) - m) * zinv;
            unsigned u = Hu[(s << 6) + lane];
            a0 += bf_lo(u) * al; a1 += bf_hi(u) * al;
        }
    }
    a0 += b0; a1 += b1;
    int f = lane * 2;
    float2 bv = *(const float2*)(bias + f);
    float o0 = selu_f(a0 + bv.x), o1 = selu_f(a1 + bv.y);
    if (OUT_BF16) {
        unsigned pk = ((unsigned)f2bf(o1) << 16) | f2bf(o0);
        ((unsigned*)outp)[(v << 6) + lane] = pk;
    } else {
        *(float2*)((float*)outp + (size_t)v * F + f) = make_float2(o0, o1);
    }
}

// --------- pooling (bf16 input) ---------------------------------------------
__device__ __forceinline__ int lower_bound(const int* __restrict__ b, int v) {
    int lo = 0, hi = N_NODES;
    while (lo < hi) { int mid = (lo + hi) >> 1; if (b[mid] < v) lo = mid + 1; else hi = mid; }
    return lo;
}

__global__ __launch_bounds__(128) void pool_partial(const unsigned short* __restrict__ Xb,
                                                    const int* __restrict__ batch,
                                                    float* __restrict__ gsum) {
    int g = blockIdx.x >> 3, c = blockIdx.x & 7;
    int start = lower_bound(batch, g);
    int end = lower_bound(batch, g + 1);
    int len = end - start;
    int s0 = start + (int)((long)len * c / 8);
    int s1 = start + (int)((long)len * (c + 1) / 8);
    if (s1 <= s0) return;
    int f = threadIdx.x;
    float sum = 0.f;
    for (int i = s0; i < s1; ++i)
        sum += __uint_as_float((unsigned)Xb[(size_t)i * F + f] << 16);
    atomicAdd(&gsum[g * F + f], sum);
}

__global__ __launch_bounds__(128) void pool_final(const float* __restrict__ gsum,
                                                  const int* __restrict__ batch,
                                                  float* __restrict__ pooled) {
    int g = blockIdx.x, f = threadIdx.x;
    int cnt = lower_bound(batch, g + 1) - lower_bound(batch, g);
    float c = fmaxf((float)cnt, 1.f);
    pooled[g * F + f] = selu_f(gsum[g * F + f] / c);
}

// --------- MLP head ---------------------------------------------------------
__global__ __launch_bounds__(64) void head(const float* __restrict__ pooled,
                                           const float* __restrict__ fc1w,
                                           const float* __restrict__ fc1b,
                                           const float* __restrict__ fc2w,
                                           const float* __restrict__ fc2b,
                                           float* __restrict__ out) {
    __shared__ float fs[64];
    int g = blockIdx.x, j = threadIdx.x;
    float acc = fc1b[j];
    for (int k = 0; k < F; ++k) acc += pooled[g * F + k] * fc1w[k * 64 + j];
    float f = selu_f(acc);
    fs[j] = f;
    out[128 + g * 64 + j] = f;
    __syncthreads();
    if (j < 2) {
        float l = fc2b[j];
        for (int k = 0; k < 64; ++k) l += fs[k] * fc2w[k * 2 + j];
        out[g * 2 + j] = l;
    }
}

extern "C" void kernel_launch(void* const* d_in, const int* in_sizes, int n_in,
                              void* d_out, int out_size, void* d_ws, size_t ws_size,
                              hipStream_t stream) {
    const float* x    = (const float*)d_in[0];
    const int*   ei   = (const int*)d_in[1];
    const int*   batch= (const int*)d_in[2];
    const float* W1   = (const float*)d_in[3];
    const float* as1  = (const float*)d_in[4];
    const float* ad1  = (const float*)d_in[5];
    const float* b1   = (const float*)d_in[6];
    const float* W2   = (const float*)d_in[7];
    const float* as2  = (const float*)d_in[8];
    const float* ad2  = (const float*)d_in[9];
    const float* b2   = (const float*)d_in[10];
    const float* fc1w = (const float*)d_in[11];
    const float* fc1b = (const float*)d_in[12];
    const float* fc2w = (const float*)d_in[13];
    const float* fc2b = (const float*)d_in[14];
    float* out = (float*)d_out;

    unsigned short* Xb   = (unsigned short*)d_ws;                  // N*128 bf16 (x / h1 / h2)
    unsigned short* Hb   = Xb + (size_t)N_NODES * F;               // N*128 bf16 (gather operand)
    unsigned short* W1f  = Hb + (size_t)N_NODES * F;               // 16384 bf16
    unsigned short* W2f  = W1f + 16384;                            // 16384 bf16
    float* as_    = (float*)(W2f + 16384);                         // N
    float* ad_    = as_ + N_NODES;                                 // N
    int*   deg    = (int*)(ad_ + N_NODES);                         // N (also "fill")
    int*   rowptr = deg + N_NODES;                                 // N+1
    int*   csr_src= rowptr + N_NODES + 1;                          // E_TOT
    int*   bsum   = csr_src + E_TOT;                               // SCAN_NB (pad 128)
    float* gsum   = (float*)(bsum + 128);                          // 64*128
    float* pooled = gsum + NGRAPH * F;                             // 64*128

    hipMemsetAsync(deg, 0, N_NODES * sizeof(int), stream);
    hipMemsetAsync(gsum, 0, NGRAPH * F * sizeof(float), stream);

    const int gGemm = (N_NODES + 63) / 64;    // 1563
    const int gNode = (N_NODES + 3) / 4;      // wave per node
    const int gEdge = (E_TOT + 255) / 256;

    // ---- prep: convert x, pack weights, build CSR ----
    cvt_bf16<<<(N_NODES * F / 8 + 255) / 256, 256, 0, stream>>>(x, Xb);
    pack_w<<<8, 256, 0, stream>>>(W1, W1f);
    pack_w<<<8, 256, 0, stream>>>(W2, W2f);
    hist<<<gEdge, 256, 0, stream>>>(ei, deg);
    scan_a<<<SCAN_NB, 256, 0, stream>>>(deg, rowptr, bsum);
    scan_b<<<1, 128, 0, stream>>>(bsum);
    scan_c<<<SCAN_NB, 256, 0, stream>>>(rowptr, bsum);
    hipMemsetAsync(deg, 0, N_NODES * sizeof(int), stream);   // reuse as fill
    scatter<<<gEdge, 256, 0, stream>>>(ei, rowptr, deg, csr_src);

    // ---- layer 1: Xb -> Hb + dots ; aggregate -> Xb (bf16 h1) ----
    gemm_mfma<<<gGemm, 256, 0, stream>>>(Xb, W1f, as1, ad1, Hb, as_, ad_);
    gat_csr<true><<<gNode, 256, 0, stream>>>(rowptr, csr_src, as_, ad_, Hb, b1, Xb);

    // ---- layer 2: Xb -> Hb + dots ; aggregate -> Xb (bf16 h2) ----
    gemm_mfma<<<gGemm, 256, 0, stream>>>(Xb, W2f, as2, ad2, Hb, as_, ad_);
    gat_csr<true><<<gNode, 256, 0, stream>>>(rowptr, csr_src, as_, ad_, Hb, b2, Xb);

    // ---- pool + head ----
    pool_partial<<<NGRAPH * 8, 128, 0, stream>>>(Xb, batch, gsum);
    pool_final<<<NGRAPH, 128, 0, stream>>>(gsum, batch, pooled);
    head<<<NGRAPH, 64, 0, stream>>>(pooled, fc1w, fc1b, fc2w, fc2b, out);
}

// Round 6
// 349.622 us; speedup vs baseline: 9.6432x; 1.4007x over previous
//
#include <hip/hip_runtime.h>
#include <hip/hip_bf16.h>

#define N_NODES 100000
#define N_EDGES 1600000
#define E_TOT   (N_EDGES + N_NODES)   // edges + self loops
#define F 128
#define NGRAPH 64
#define NEG_SLOPE 0.2f
#define SELU_SCALE 1.0507009873554805f
#define SELU_ALPHA 1.6732632423543772f

#define BSZ 256                        // nodes per bucket
#define NB  391                        // ceil(N_NODES/BSZ)
#define CHUNK 4096                     // edges per scatter block
#define NCHUNK 416                     // ceil(E_TOT/CHUNK)
#define LCAP 8192                      // LDS staging cap (mean bucket=4352, sd~66)

typedef __attribute__((ext_vector_type(8))) short bf16x8;
typedef __attribute__((ext_vector_type(4))) float f32x4;

__device__ __forceinline__ float selu_f(float x) {
    return x > 0.f ? SELU_SCALE * x : SELU_SCALE * SELU_ALPHA * (expf(x) - 1.f);
}
__device__ __forceinline__ float lrelu(float x) {
    return x > 0.f ? x : NEG_SLOPE * x;
}
__device__ __forceinline__ unsigned short f2bf(float f) {   // RNE
    unsigned u = __float_as_uint(f);
    return (unsigned short)((u + 0x7FFFu + ((u >> 16) & 1u)) >> 16);
}
__device__ __forceinline__ float bf_lo(unsigned u) { return __uint_as_float(u << 16); }
__device__ __forceinline__ float bf_hi(unsigned u) { return __uint_as_float(u & 0xFFFF0000u); }

// ---------------- f32 -> bf16 convert (x input) -----------------------------
__global__ __launch_bounds__(256) void cvt_bf16(const float* __restrict__ X,
                                                unsigned short* __restrict__ Xb) {
    int i = blockIdx.x * 256 + threadIdx.x;
    if (i >= N_NODES * F / 8) return;
    const float4* Xp = (const float4*)X;
    float4 v0 = Xp[i * 2], v1 = Xp[i * 2 + 1];
    uint4 o;
    o.x = ((unsigned)f2bf(v0.y) << 16) | f2bf(v0.x);
    o.y = ((unsigned)f2bf(v0.w) << 16) | f2bf(v0.z);
    o.z = ((unsigned)f2bf(v1.y) << 16) | f2bf(v1.x);
    o.w = ((unsigned)f2bf(v1.w) << 16) | f2bf(v1.z);
    ((uint4*)Xb)[i] = o;
}

// --------- pack W[128][128] f32 into MFMA B-fragment order, bf16 ------------
__global__ __launch_bounds__(256) void pack_w(const float* __restrict__ W,
                                              unsigned short* __restrict__ Wf) {
    int i = blockIdx.x * 256 + threadIdx.x;            // 2048
    if (i >= 2048) return;
    int l = i & 63, t = (i >> 6) & 3, nt = i >> 8;
    int kb = t * 32 + (l >> 4) * 8;
    int n  = nt * 16 + (l & 15);
    unsigned short o[8];
#pragma unroll
    for (int j = 0; j < 8; ++j) o[j] = f2bf(W[(size_t)(kb + j) * F + n]);
    uint4 p;
    p.x = ((unsigned)o[1] << 16) | o[0];
    p.y = ((unsigned)o[3] << 16) | o[2];
    p.z = ((unsigned)o[5] << 16) | o[4];
    p.w = ((unsigned)o[7] << 16) | o[6];
    ((uint4*)Wf)[i] = p;
}

// ------ MFMA GEMM: Hb = bf16(Xb @ W) + attention dots, no LDS ---------------
__global__ __launch_bounds__(256) void gemm_mfma(const unsigned short* __restrict__ Xb,
                                                 const unsigned short* __restrict__ Wf,
                                                 const float* __restrict__ avs,
                                                 const float* __restrict__ avd,
                                                 unsigned short* __restrict__ Hb,
                                                 float* __restrict__ as_,
                                                 float* __restrict__ ad_) {
    int w = threadIdx.x >> 6, l = threadIdx.x & 63;
    int row0 = blockIdx.x * 64 + w * 16;
    int arow = row0 + (l & 15);
    int arow_c = arow < N_NODES ? arow : N_NODES - 1;   // clamp loads
    f32x4 acc[8] = {};
#pragma unroll
    for (int t = 0; t < 4; ++t) {
        bf16x8 a = *(const bf16x8*)(Xb + (size_t)arow_c * F + t * 32 + (l >> 4) * 8);
#pragma unroll
        for (int nt = 0; nt < 8; ++nt) {
            bf16x8 b = *(const bf16x8*)(Wf + (size_t)((nt * 4 + t) * 64 + l) * 8);
            acc[nt] = __builtin_amdgcn_mfma_f32_16x16x32_bf16(a, b, acc[nt], 0, 0, 0);
        }
    }
    int c = l & 15;
    float ps[4] = {}, pd[4] = {};
#pragma unroll
    for (int nt = 0; nt < 8; ++nt) {
        float ws = avs[nt * 16 + c];
        float wd = avd[nt * 16 + c];
#pragma unroll
        for (int r = 0; r < 4; ++r) {
            int grow = row0 + (l >> 4) * 4 + r;
            if (grow < N_NODES)
                Hb[(size_t)grow * F + nt * 16 + c] = f2bf(acc[nt][r]);
            ps[r] += acc[nt][r] * ws;
            pd[r] += acc[nt][r] * wd;
        }
    }
#pragma unroll
    for (int r = 0; r < 4; ++r) {
#pragma unroll
        for (int off = 1; off < 16; off <<= 1) {
            ps[r] += __shfl_xor(ps[r], off);
            pd[r] += __shfl_xor(pd[r], off);
        }
    }
    if (c == 0) {
#pragma unroll
        for (int r = 0; r < 4; ++r) {
            int grow = row0 + (l >> 4) * 4 + r;
            if (grow < N_NODES) { as_[grow] = ps[r]; ad_[grow] = pd[r]; }
        }
    }
}

// ================= bucketed CSR build (no per-edge global atomics) ==========
// bucket b = dst >> 8 (391 buckets x 256 nodes)

__global__ __launch_bounds__(256) void hist1(const int* __restrict__ ei,
                                             int* __restrict__ gh) {
    __shared__ int lh[NB];
    for (int i = threadIdx.x; i < NB; i += 256) lh[i] = 0;
    __syncthreads();
    int base = blockIdx.x * CHUNK;
#pragma unroll
    for (int k = 0; k < 16; ++k) {
        int i = base + k * 256 + threadIdx.x;
        if (i < E_TOT) {
            int d = (i < N_EDGES) ? ei[N_EDGES + i] : i - N_EDGES;
            atomicAdd(&lh[d >> 8], 1);
        }
    }
    __syncthreads();
    for (int i = threadIdx.x; i < NB; i += 256)
        if (lh[i]) atomicAdd(&gh[i], lh[i]);
}

__global__ __launch_bounds__(512) void scan1(const int* __restrict__ gh,
                                             int* __restrict__ bbase,
                                             int* __restrict__ cursor,
                                             int* __restrict__ rowptr) {
    __shared__ int ts[512];
    int t = threadIdx.x;
    int v = (t < NB) ? gh[t] : 0;
    ts[t] = v;
    __syncthreads();
    for (int off = 1; off < 512; off <<= 1) {
        int u = (t >= off) ? ts[t - off] : 0;
        __syncthreads();
        ts[t] += u;
        __syncthreads();
    }
    if (t < NB) { int ex = ts[t] - v; bbase[t] = ex; cursor[t] = ex; }
    if (t == 0) rowptr[N_NODES] = E_TOT;
}

__global__ __launch_bounds__(256) void scatter1(const int* __restrict__ ei,
                                                int* __restrict__ cursor,
                                                unsigned* __restrict__ packed) {
    __shared__ int lh[NB], lbase[NB];
    for (int i = threadIdx.x; i < NB; i += 256) lh[i] = 0;
    __syncthreads();
    int base = blockIdx.x * CHUNK;
#pragma unroll
    for (int k = 0; k < 16; ++k) {
        int i = base + k * 256 + threadIdx.x;
        if (i < E_TOT) {
            int d = (i < N_EDGES) ? ei[N_EDGES + i] : i - N_EDGES;
            atomicAdd(&lh[d >> 8], 1);
        }
    }
    __syncthreads();
    for (int i = threadIdx.x; i < NB; i += 256) {
        int cn = lh[i];
        lbase[i] = cn ? atomicAdd(&cursor[i], cn) : 0;
        lh[i] = 0;
    }
    __syncthreads();
#pragma unroll
    for (int k = 0; k < 16; ++k) {
        int i = base + k * 256 + threadIdx.x;
        if (i < E_TOT) {
            int s, d;
            if (i < N_EDGES) { s = ei[i]; d = ei[N_EDGES + i]; }
            else             { s = d = i - N_EDGES; }
            int b = d >> 8;
            int r = atomicAdd(&lh[b], 1);
            packed[lbase[b] + r] = (unsigned)s | ((unsigned)(d & 255) << 20);
        }
    }
}

// one block per bucket: LDS counting sort over 256 local nodes -> rowptr + csr_src
__global__ __launch_bounds__(256) void build2(const int* __restrict__ gh,
                                              const int* __restrict__ bbase,
                                              const unsigned* __restrict__ packed,
                                              int* __restrict__ rowptr,
                                              int* __restrict__ csr_src) {
    __shared__ int sh_hist[BSZ], sh_row[BSZ], ts[BSZ];
    __shared__ int lsrc[LCAP];
    int b = blockIdx.x, t = threadIdx.x;
    int node0 = b << 8;
    int nn = min(BSZ, N_NODES - node0);
    int base = bbase[b], cnt = gh[b];
    sh_hist[t] = 0;
    __syncthreads();
    for (int j = t; j < cnt; j += 256)
        atomicAdd(&sh_hist[packed[base + j] >> 20], 1);
    __syncthreads();
    int v = sh_hist[t];
    ts[t] = v;
    __syncthreads();
    for (int off = 1; off < 256; off <<= 1) {
        int u = (t >= off) ? ts[t - off] : 0;
        __syncthreads();
        ts[t] += u;
        __syncthreads();
    }
    sh_row[t] = ts[t] - v;                      // exclusive scan
    if (t < nn) rowptr[node0 + t] = base + sh_row[t];
    sh_hist[t] = 0;
    __syncthreads();
    if (cnt <= LCAP) {
        for (int j = t; j < cnt; j += 256) {
            unsigned u = packed[base + j];
            int dlo = u >> 20;
            int r = atomicAdd(&sh_hist[dlo], 1);
            lsrc[sh_row[dlo] + r] = (int)(u & 0xFFFFFu);
        }
        __syncthreads();
        for (int j = t; j < cnt; j += 256) csr_src[base + j] = lsrc[j];
    } else {                                     // never expected; correctness guard
        for (int j = t; j < cnt; j += 256) {
            unsigned u = packed[base + j];
            int dlo = u >> 20;
            int r = atomicAdd(&sh_hist[dlo], 1);
            csr_src[base + sh_row[dlo] + r] = (int)(u & 0xFFFFFu);
        }
    }
}

// ------- fused per-dst softmax + aggregation + bias + SELU ------------------
template <bool OUT_BF16>
__global__ __launch_bounds__(256) void gat_csr(const int* __restrict__ rowptr,
                                               const int* __restrict__ csr_src,
                                               const float* __restrict__ as_,
                                               const float* __restrict__ ad_,
                                               const unsigned short* __restrict__ Hb,
                                               const float* __restrict__ bias,
                                               void* __restrict__ outp) {
    int v = (blockIdx.x * 256 + threadIdx.x) >> 6;
    int lane = threadIdx.x & 63;
    if (v >= N_NODES) return;
    int start = rowptr[v];
    int deg = rowptr[v + 1] - start;
    float ad_v = ad_[v];
    float a0 = 0.f, a1 = 0.f, b0 = 0.f, b1 = 0.f;
    const unsigned* Hu = (const unsigned*)Hb;   // 2 bf16 per dword

    if (deg <= 64) {
        int  s_reg = (lane < deg) ? csr_src[start + lane] : 0;
        float ev   = (lane < deg) ? lrelu(as_[s_reg] + ad_v) : -__builtin_inff();
        float m = ev;
#pragma unroll
        for (int off = 1; off < 64; off <<= 1) m = fmaxf(m, __shfl_xor(m, off));
        float ex = (lane < deg) ? expf(ev - m) : 0.f;
        float zs = ex;
#pragma unroll
        for (int off = 1; off < 64; off <<= 1) zs += __shfl_xor(zs, off);
        float al_l = ex / zs;                    // per-lane alpha
        int e = 0;
        for (; e + 8 <= deg; e += 8) {           // 8 gathers in flight
            float lv[8]; int sv[8]; unsigned uv[8];
#pragma unroll
            for (int q = 0; q < 8; ++q) {
                lv[q] = __shfl(al_l, e + q);
                sv[q] = __shfl(s_reg, e + q);
            }
#pragma unroll
            for (int q = 0; q < 8; ++q) uv[q] = Hu[(sv[q] << 6) + lane];
#pragma unroll
            for (int q = 0; q < 8; ++q) {
                if (q & 1) { b0 += bf_lo(uv[q]) * lv[q]; b1 += bf_hi(uv[q]) * lv[q]; }
                else       { a0 += bf_lo(uv[q]) * lv[q]; a1 += bf_hi(uv[q]) * lv[q]; }
            }
        }
        for (; e < deg; ++e) {
            float al = __shfl(al_l, e);
            int   s  = __shfl(s_reg, e);
            unsigned u = Hu[(s << 6) + lane];
            a0 += bf_lo(u) * al; a1 += bf_hi(u) * al;
        }
    } else {
        float m = -__builtin_inff();
        for (int e = start + lane; e < start + deg; e += 64)
            m = fmaxf(m, lrelu(as_[csr_src[e]] + ad_v));
#pragma unroll
        for (int off = 1; off < 64; off <<= 1) m = fmaxf(m, __shfl_xor(m, off));
        float zs = 0.f;
        for (int e = start + lane; e < start + deg; e += 64)
            zs += expf(lrelu(as_[csr_src[e]] + ad_v) - m);
#pragma unroll
        for (int off = 1; off < 64; off <<= 1) zs += __shfl_xor(zs, off);
        float zinv = 1.f / zs;
        for (int e = start; e < start + deg; ++e) {
            int s = csr_src[e];
            float al = expf(lrelu(as_[s] + ad_v) - m) * zinv;
            unsigned u = Hu[(s << 6) + lane];
            a0 += bf_lo(u) * al; a1 += bf_hi(u) * al;
        }
    }
    a0 += b0; a1 += b1;
    int f = lane * 2;
    float2 bv = *(const float2*)(bias + f);
    float o0 = selu_f(a0 + bv.x), o1 = selu_f(a1 + bv.y);
    if (OUT_BF16) {
        unsigned pk = ((unsigned)f2bf(o1) << 16) | f2bf(o0);
        ((unsigned*)outp)[(v << 6) + lane] = pk;
    } else {
        *(float2*)((float*)outp + (size_t)v * F + f) = make_float2(o0, o1);
    }
}

// --------- pooling (bf16 input) ---------------------------------------------
__device__ __forceinline__ int lower_bound(const int* __restrict__ b, int v) {
    int lo = 0, hi = N_NODES;
    while (lo < hi) { int mid = (lo + hi) >> 1; if (b[mid] < v) lo = mid + 1; else hi = mid; }
    return lo;
}

__global__ __launch_bounds__(128) void pool_partial(const unsigned short* __restrict__ Xb,
                                                    const int* __restrict__ batch,
                                                    float* __restrict__ gsum) {
    int g = blockIdx.x >> 3, c = blockIdx.x & 7;
    int start = lower_bound(batch, g);
    int end = lower_bound(batch, g + 1);
    int len = end - start;
    int s0 = start + (int)((long)len * c / 8);
    int s1 = start + (int)((long)len * (c + 1) / 8);
    if (s1 <= s0) return;
    int f = threadIdx.x;
    float sum = 0.f;
    for (int i = s0; i < s1; ++i)
        sum += __uint_as_float((unsigned)Xb[(size_t)i * F + f] << 16);
    atomicAdd(&gsum[g * F + f], sum);
}

__global__ __launch_bounds__(128) void pool_final(const float* __restrict__ gsum,
                                                  const int* __restrict__ batch,
                                                  float* __restrict__ pooled) {
    int g = blockIdx.x, f = threadIdx.x;
    int cnt = lower_bound(batch, g + 1) - lower_bound(batch, g);
    float c = fmaxf((float)cnt, 1.f);
    pooled[g * F + f] = selu_f(gsum[g * F + f] / c);
}

// --------- MLP head ---------------------------------------------------------
__global__ __launch_bounds__(64) void head(const float* __restrict__ pooled,
                                           const float* __restrict__ fc1w,
                                           const float* __restrict__ fc1b,
                                           const float* __restrict__ fc2w,
                                           const float* __restrict__ fc2b,
                                           float* __restrict__ out) {
    __shared__ float fs[64];
    int g = blockIdx.x, j = threadIdx.x;
    float acc = fc1b[j];
    for (int k = 0; k < F; ++k) acc += pooled[g * F + k] * fc1w[k * 64 + j];
    float f = selu_f(acc);
    fs[j] = f;
    out[128 + g * 64 + j] = f;
    __syncthreads();
    if (j < 2) {
        float l = fc2b[j];
        for (int k = 0; k < 64; ++k) l += fs[k] * fc2w[k * 2 + j];
        out[g * 2 + j] = l;
    }
}

extern "C" void kernel_launch(void* const* d_in, const int* in_sizes, int n_in,
                              void* d_out, int out_size, void* d_ws, size_t ws_size,
                              hipStream_t stream) {
    const float* x    = (const float*)d_in[0];
    const int*   ei   = (const int*)d_in[1];
    const int*   batch= (const int*)d_in[2];
    const float* W1   = (const float*)d_in[3];
    const float* as1  = (const float*)d_in[4];
    const float* ad1  = (const float*)d_in[5];
    const float* b1   = (const float*)d_in[6];
    const float* W2   = (const float*)d_in[7];
    const float* as2  = (const float*)d_in[8];
    const float* ad2  = (const float*)d_in[9];
    const float* b2   = (const float*)d_in[10];
    const float* fc1w = (const float*)d_in[11];
    const float* fc1b = (const float*)d_in[12];
    const float* fc2w = (const float*)d_in[13];
    const float* fc2b = (const float*)d_in[14];
    float* out = (float*)d_out;

    unsigned short* Xb   = (unsigned short*)d_ws;                  // N*128 bf16
    unsigned short* Hb   = Xb + (size_t)N_NODES * F;               // N*128 bf16
    unsigned short* W1f  = Hb + (size_t)N_NODES * F;               // 16384 bf16
    unsigned short* W2f  = W1f + 16384;                            // 16384 bf16
    float* as_    = (float*)(W2f + 16384);                         // N
    float* ad_    = as_ + N_NODES;                                 // N
    int*   rowptr = (int*)(ad_ + N_NODES);                         // N+1
    int*   csr_src= rowptr + N_NODES + 1;                          // E_TOT
    unsigned* packed = (unsigned*)(csr_src + E_TOT);               // E_TOT
    int*   gh     = (int*)(packed + E_TOT);                        // NB
    int*   bbase  = gh + NB;                                       // NB
    int*   cursor = bbase + NB;                                    // NB
    float* gsum   = (float*)(cursor + NB + 64);                    // 64*128
    float* pooled = gsum + NGRAPH * F;                             // 64*128

    hipMemsetAsync(gh, 0, NB * sizeof(int), stream);
    hipMemsetAsync(gsum, 0, NGRAPH * F * sizeof(float), stream);

    const int gGemm = (N_NODES + 63) / 64;    // 1563
    const int gNode = (N_NODES + 3) / 4;      // wave per node

    // ---- prep: convert x, pack weights ----
    cvt_bf16<<<(N_NODES * F / 8 + 255) / 256, 256, 0, stream>>>(x, Xb);
    pack_w<<<8, 256, 0, stream>>>(W1, W1f);
    pack_w<<<8, 256, 0, stream>>>(W2, W2f);

    // ---- bucketed CSR build ----
    hist1<<<NCHUNK, 256, 0, stream>>>(ei, gh);
    scan1<<<1, 512, 0, stream>>>(gh, bbase, cursor, rowptr);
    scatter1<<<NCHUNK, 256, 0, stream>>>(ei, cursor, packed);
    build2<<<NB, 256, 0, stream>>>(gh, bbase, packed, rowptr, csr_src);

    // ---- layer 1: Xb -> Hb + dots ; aggregate -> Xb (bf16 h1) ----
    gemm_mfma<<<gGemm, 256, 0, stream>>>(Xb, W1f, as1, ad1, Hb, as_, ad_);
    gat_csr<true><<<gNode, 256, 0, stream>>>(rowptr, csr_src, as_, ad_, Hb, b1, Xb);

    // ---- layer 2: Xb -> Hb + dots ; aggregate -> Xb (bf16 h2) ----
    gemm_mfma<<<gGemm, 256, 0, stream>>>(Xb, W2f, as2, ad2, Hb, as_, ad_);
    gat_csr<true><<<gNode, 256, 0, stream>>>(rowptr, csr_src, as_, ad_, Hb, b2, Xb);

    // ---- pool + head ----
    pool_partial<<<NGRAPH * 8, 128, 0, stream>>>(Xb, batch, gsum);
    pool_final<<<NGRAPH, 128, 0, stream>>>(gsum, batch, pooled);
    head<<<NGRAPH, 64, 0, stream>>>(pooled, fc1w, fc1b, fc2w, fc2b, out);
}